// Round 14
// baseline (401.480 us; speedup 1.0000x reference)
//
#include <hip/hip_runtime.h>
#include <cmath>

// CRSDCell bf16-MFMA pipeline, round 14: k_fused at 3 blocks/CU via
// launch_bounds(512,6) (reg cap 84). Register cuts that make it fit:
//  (a) half-step K=16 pipeline -> B dbuf 2x[2] frags (16 VGPR, was 64),
//  (b) htp[2][8] deleted -> epi2 reconstructs h~ = z*sdev + mean from the
//      h_norm bf16 already in LDS + persisted LN stats (bf16-equal error).
//  - Panels staged once (k-slot layout); GEMM K-loops barrier-free.
//  - Weights pre-packed chunk-major P[k0][slot4][n][8]; bwp/uwp contiguous.
//  - k_rk: fused r_seq + k/q partials (unchanged, (512,4)).
// FFT folds exactly: irfft(rfft(h)*s) = s*h. h_prev=r_prev=0 kills Wh/A terms.

typedef __attribute__((ext_vector_type(8)))  short short8;
typedef __attribute__((ext_vector_type(16))) float f32x16;

__device__ __forceinline__ unsigned short f2bf(float f) {
  union { float f; unsigned u; } v; v.f = f;
  unsigned r = v.u + 0x7FFF + ((v.u >> 16) & 1);   // RTNE
  return (unsigned short)(r >> 16);
}
__device__ __forceinline__ unsigned cvtpk(float lo, float hi) {
  unsigned r;
  asm("v_cvt_pk_bf16_f32 %0, %1, %2" : "=v"(r) : "v"(lo), "v"(hi));
  return r;
}
__device__ __forceinline__ float bf2f(unsigned short h) {
  union { unsigned u; float f; } v; v.u = ((unsigned)h) << 16; return v.f;
}
__device__ __forceinline__ f32x16 mfma16(short8 a, short8 b, f32x16 c) {
  return __builtin_amdgcn_mfma_f32_32x32x16_bf16(a, b, c, 0, 0, 0);
}
__device__ __forceinline__ void barrier_lgkm() {
  asm volatile("s_waitcnt lgkmcnt(0)" ::: "memory");
  __builtin_amdgcn_s_barrier();
  __builtin_amdgcn_sched_barrier(0);
}

// ---------------- weight convert + pack ----------------
// packed offset for (n,k) in [N][K]: (k>>5)*N*32 + ((k>>3)&3)*N*8 + n*8 + (k&7)
__global__ __launch_bounds__(256) void k_wconv(
    const float* __restrict__ wx, const float* __restrict__ key,
    const float* __restrict__ bw, const float* __restrict__ uw,
    const float* __restrict__ fftpw, const float* __restrict__ fg,
    unsigned short* __restrict__ wxp, unsigned short* __restrict__ keyp,
    unsigned short* __restrict__ bwp, unsigned short* __restrict__ uwp,
    unsigned short* __restrict__ fftps) {
  int i = blockIdx.x * 256 + threadIdx.x;
  if (i >= 884736) return;
  float v; int n, k, N; unsigned short* dst;
  if (i < 131072)      { int j = i;          N = 512; k = j & 255; n = j >> 8; v = wx[j];  dst = wxp; }
  else if (i < 229376) { int j = i - 131072; N = 128; k = j % 768; n = j / 768; v = key[j]; dst = keyp; }
  else if (i < 491520) { int j = i - 229376; N = 512; k = j & 511; n = j >> 9; v = bw[j];  dst = bwp; }
  else if (i < 622592) { int j = i - 491520; N = 512; k = j & 255; n = j >> 8; v = uw[j];  dst = uwp; }
  else                 { int j = i - 622592; N = 512; k = j & 511; n = j >> 9; v = fftpw[j] * fg[k]; dst = fftps; }
  dst[(k >> 5) * (N * 32) + ((k >> 3) & 3) * (N * 8) + n * 8 + (k & 7)] = f2bf(v);
}

// ---------------- K_RK: r_seq + k/q partials (BM=32) ----------------
// LDS: sRX = [r slots 0..63 | x slots 64..95] (48KB), red 2.5KB
__global__ __launch_bounds__(512, 4) void k_rk(
    const float* __restrict__ x, const unsigned short* __restrict__ wxp,
    const unsigned short* __restrict__ keyp,
    const float* __restrict__ wxb, const float* __restrict__ resa,
    const float* __restrict__ rng, const float* __restrict__ rnb,
    const float* __restrict__ keyb,
    float* __restrict__ rout, float* __restrict__ partial) {
  __shared__ short sRX[24576];  // r 32x512 @0, x 32x256 @16384; kp overlays
  __shared__ float red[640];
  const int t = threadIdx.x, w = t >> 6, lane = t & 63, lr = lane & 31, lh = lane >> 5;
  const int m0 = blockIdx.x * 32;

  // ---- stage x panel (slots 64..95) ----
#pragma unroll
  for (int i = 0; i < 4; ++i) {
    int c = t + i * 512;                 // float4 idx; 64 per row
    int row = c >> 6, k0 = (c & 63) * 4;
    float4 v = *reinterpret_cast<const float4*>(x + (size_t)(m0 + row) * 256 + k0);
    uint2 p;
    p.x = cvtpk(v.x, v.y);
    p.y = cvtpk(v.z, v.w);
    *reinterpret_cast<uint2*>(&sRX[16384 + (k0 >> 3) * 256 + row * 8 + (k0 & 7)]) = p;
  }
  barrier_lgkm();

  // ---- GEMM0: r_pre = x @ Wx^T, 8 barrier-free steps ----
  f32x16 acc[2];
#pragma unroll
  for (int ni = 0; ni < 2; ++ni)
#pragma unroll
    for (int e = 0; e < 16; ++e) acc[ni][e] = 0.f;
  short8 b0[4], b1[4];
  auto loadB0 = [&](int s, short8 (&bd)[4]) {
#pragma unroll
    for (int kh = 0; kh < 2; ++kh)
#pragma unroll
      for (int ni = 0; ni < 2; ++ni)
        bd[kh * 2 + ni] = *reinterpret_cast<const short8*>(
            wxp + (size_t)s * 16384 + (kh * 2 + lh) * 4096 + (64 * w + 32 * ni + lr) * 8);
  };
  auto mf0 = [&](int s, short8 (&bc)[4]) {
    short8 af[2];
#pragma unroll
    for (int kh = 0; kh < 2; ++kh)
      af[kh] = *reinterpret_cast<const short8*>(
          &sRX[16384 + (s * 4 + kh * 2 + lh) * 256 + lr * 8]);
    __builtin_amdgcn_s_setprio(1);
#pragma unroll
    for (int kh = 0; kh < 2; ++kh)
#pragma unroll
      for (int ni = 0; ni < 2; ++ni)
        acc[ni] = mfma16(af[kh], bc[kh * 2 + ni], acc[ni]);
    __builtin_amdgcn_s_setprio(0);
  };
  loadB0(0, b0);
#pragma unroll
  for (int s = 0; s < 8; s += 2) {
    loadB0(s + 1, b1);
    mf0(s, b0);
    if (s + 2 < 8) loadB0(s + 2, b0);
    mf0(s + 1, b1);
  }

  // ---- epi0: z=(1-a)tanh(.+b), LN, write rout + r panel ----
#pragma unroll
  for (int ni = 0; ni < 2; ++ni) {
    int col = 64 * w + 32 * ni + lr;
    float al = 1.f / (1.f + expf(-resa[col >> 7]));
    float oma = 1.f - al, bbv = wxb[col];
#pragma unroll
    for (int r = 0; r < 16; ++r)
      acc[ni][r] = oma * tanhf(acc[ni][r] + bbv);
  }
#pragma unroll
  for (int r = 0; r < 16; ++r) {
    float s1 = acc[0][r] + acc[1][r];
    float s2 = acc[0][r] * acc[0][r] + acc[1][r] * acc[1][r];
#pragma unroll
    for (int m = 1; m <= 16; m <<= 1) { s1 += __shfl_xor(s1, m); s2 += __shfl_xor(s2, m); }
    int rl = (r & 3) + 8 * (r >> 2) + 4 * lh;
    if (lr == r) { red[w * 32 + rl] = s1; red[256 + w * 32 + rl] = s2; }
  }
  __syncthreads();
  if (t < 32) {
    float s1 = 0.f, s2 = 0.f;
#pragma unroll
    for (int n = 0; n < 8; ++n) { s1 += red[n * 32 + t]; s2 += red[256 + n * 32 + t]; }
    float mean = s1 * (1.f / 512.f);
    float var = s2 * (1.f / 512.f) - mean * mean;
    float rstd = rsqrtf(var + 1e-5f);
    red[512 + t * 2] = mean;
    red[512 + t * 2 + 1] = rstd;
  }
  __syncthreads();
#pragma unroll
  for (int q = 0; q < 4; ++q) {
    float4 stA = *reinterpret_cast<float4*>(&red[512 + (8 * q + 4 * lh) * 2]);
    float4 stB = *reinterpret_cast<float4*>(&red[512 + (8 * q + 4 * lh) * 2 + 4]);
    float mean[4] = {stA.x, stA.z, stB.x, stB.z};
    float rstd[4] = {stA.y, stA.w, stB.y, stB.w};
#pragma unroll
    for (int ni = 0; ni < 2; ++ni) {
      int col = 64 * w + 32 * ni + lr;
      float g = rng[col], bbv = rnb[col];
#pragma unroll
      for (int e = 0; e < 4; ++e) {
        int r = 4 * q + e;
        int rloc = 8 * q + 4 * lh + e;
        float val = (acc[ni][r] - mean[e]) * rstd[e] * g + bbv;
        rout[(size_t)(m0 + rloc) * 512 + col] = val;
        sRX[(col >> 3) * 256 + rloc * 8 + (col & 7)] = (short)f2bf(val);
      }
    }
  }
  barrier_lgkm();

  // ---- GEMM_k: k = [r,x] @ key^T, split-K over 2 wave-groups ----
  const int g = w >> 2, nw2 = w & 3;     // group, wave-in-group (32 cols each)
  f32x16 ak;
#pragma unroll
  for (int e = 0; e < 16; ++e) ak[e] = 0.f;
  short8 kb0[2], kb1[2];
  auto loadBk = [&](int gc, short8 (&bd)[2]) {
#pragma unroll
    for (int kh = 0; kh < 2; ++kh)
      bd[kh] = *reinterpret_cast<const short8*>(
          keyp + (size_t)gc * 4096 + (kh * 2 + lh) * 1024 + (32 * nw2 + lr) * 8);
  };
  auto mfk = [&](int gc, short8 (&bc)[2]) {
    short8 af[2];
#pragma unroll
    for (int kh = 0; kh < 2; ++kh)
      af[kh] = *reinterpret_cast<const short8*>(
          &sRX[(gc * 4 + kh * 2 + lh) * 256 + lr * 8]);
    __builtin_amdgcn_s_setprio(1);
#pragma unroll
    for (int kh = 0; kh < 2; ++kh)
      ak = mfma16(af[kh], bc[kh], ak);
    __builtin_amdgcn_s_setprio(0);
  };
  const int gbase = g * 12;
  loadBk(gbase, kb0);
#pragma unroll
  for (int s = 0; s < 12; s += 2) {
    loadBk(gbase + s + 1, kb1);
    mfk(gbase + s, kb0);
    if (s + 2 < 12) loadBk(gbase + s + 2, kb0);
    mfk(gbase + s + 1, kb1);
  }
  __syncthreads();                        // all panel reads done
  float* kp = reinterpret_cast<float*>(sRX);  // kp[g][32 rows][128 cols]
#pragma unroll
  for (int r = 0; r < 16; ++r) {
    int rr = (r & 3) + 8 * (r >> 2) + 4 * lh;
    kp[g * 4096 + rr * 128 + nw2 * 32 + lr] = ak[r];
  }
  __syncthreads();
  // pass1: per-row sumsq -> scale
  {
    int rr = t >> 4, cg = t & 15;
    float s1 = 0.f;
#pragma unroll
    for (int j = 0; j < 8; ++j) {
      int c = cg * 8 + j;
      float v = kp[rr * 128 + c] + kp[4096 + rr * 128 + c] + keyb[c];
      s1 += v * v;
    }
#pragma unroll
    for (int m = 1; m <= 8; m <<= 1) s1 += __shfl_xor(s1, m);
    if (cg == 0) red[rr] = 1.f / fmaxf(sqrtf(s1), 1e-8f);
  }
  __syncthreads();
  // pass2: column partials of l2norm(k)
  if (t < 128) {
    float p = 0.f;
    float bb = keyb[t];
#pragma unroll 4
    for (int rr = 0; rr < 32; ++rr)
      p += (kp[rr * 128 + t] + kp[4096 + rr * 128 + t] + bb) * red[rr];
    partial[(size_t)blockIdx.x * 128 + t] = p;
  }
}

// ---------------- q reduce (2048 partial blocks, 256 per batch) -------------
__global__ __launch_bounds__(256) void k_qred(const float* __restrict__ partial,
                                              float* __restrict__ q_ws) {
  int gid = blockIdx.x * 256 + threadIdx.x;   // 0..1023
  int b = gid >> 7, c = gid & 127;
  float s = 0.f;
  for (int i = 0; i < 256; ++i) s += partial[(size_t)(b * 256 + i) * 128 + c];
  q_ws[gid] = s * (1.f / 8192.f);
}

// ---------------- cvec = fftn_b @ fftp_w^T (raw fftp) ----------------
__global__ __launch_bounds__(256) void k_cvec(const float* __restrict__ fb,
                                              const float* __restrict__ fftpw,
                                              float* __restrict__ cvec) {
  int o = blockIdx.x * 256 + threadIdx.x;     // 0..511
  const float* w = fftpw + (size_t)o * 512;
  float s = 0.f;
  for (int k = 0; k < 512; ++k) s += fb[k] * w[k];
  cvec[o] = s;
}

// ---------------- memory (episodic + hebbian) ----------------
__global__ __launch_bounds__(256) void k_mem(
    const float* __restrict__ q_ws, const float* __restrict__ mkeys,
    const float* __restrict__ mvals, const float* __restrict__ hebH,
    const float* __restrict__ rmw, const float* __restrict__ rmb,
    const float* __restrict__ mixl, float* __restrict__ hm) {
  const int b = blockIdx.x, t = threadIdx.x;
  __shared__ float qv[128];
  __shared__ float ssim[256];
  __shared__ float red[256];
  __shared__ float tval[8];
  __shared__ int tidx[8];
  __shared__ float wsm[8];
  __shared__ float vcs[128];

  if (t < 128) qv[t] = q_ws[b * 128 + t];
  __syncthreads();
  red[t] = (t < 128) ? qv[t] * qv[t] : 0.f;
  __syncthreads();
  for (int s = 128; s > 0; s >>= 1) {
    if (t < s) red[t] += red[t + s];
    __syncthreads();
  }
  float qsc = 1.f / fmaxf(sqrtf(red[0]), 1e-8f);
  {
    const float* mk = mkeys + ((size_t)b * 256 + t) * 128;
    float dot = 0.f, ms = 0.f;
    for (int k = 0; k < 128; ++k) { float mv = mk[k]; dot += qv[k] * mv; ms += mv * mv; }
    ssim[t] = dot * qsc / fmaxf(sqrtf(ms), 1e-8f);
  }
  __syncthreads();
  for (int it = 0; it < 8; ++it) {
    if (t < 64) {
      float bv = -1e30f; int bi = 0;
#pragma unroll
      for (int u = 0; u < 4; ++u) {
        int m = t * 4 + u;
        float v = ssim[m];
        if (v > bv) { bv = v; bi = m; }
      }
      for (int off = 32; off; off >>= 1) {
        float ov = __shfl_xor(bv, off, 64);
        int oi = __shfl_xor(bi, off, 64);
        if (ov > bv || (ov == bv && oi < bi)) { bv = ov; bi = oi; }
      }
      if (t == 0) { tval[it] = bv; tidx[it] = bi; ssim[bi] = -1e30f; }
    }
    __syncthreads();
  }
  if (t == 0) {
    float m0 = tval[0], sum = 0.f, e[8];
#pragma unroll
    for (int i = 0; i < 8; ++i) { e[i] = expf(tval[i] - m0); sum += e[i]; }
#pragma unroll
    for (int i = 0; i < 8; ++i) wsm[i] = e[i] / sum;
  }
  __syncthreads();
  float mix = 1.f / (1.f + expf(-mixl[0]));
  if (t < 128) {
    float vh = 0.f;
#pragma unroll
    for (int i = 0; i < 8; ++i) vh += wsm[i] * mvals[((size_t)b * 256 + tidx[i]) * 128 + t];
    float vhb = 0.f;
    const float* H = hebH + (size_t)b * 128 * 128;
    for (int k = 0; k < 128; ++k) vhb += qv[k] * H[k * 128 + t];
    vcs[t] = mix * vh + (1.f - mix) * vhb;
  }
  __syncthreads();
  for (int h = t; h < 512; h += 256) {
    float sum = rmb[h];
    const float* wr = rmw + (size_t)h * 128;
    for (int v = 0; v < 128; ++v) sum += vcs[v] * wr[v];
    hm[b * 512 + h] = sum;
  }
}

// ---------------- fused h_tilde -> LN -> fftp GEMM -> hs (BM=32) ------------
// LDS: sRX = [r 0..63 | x 64..95] 48KB (h_norm overlays r) + red 2.5K
// launch_bounds(512,6): 3 blocks/CU; half-step K=16 dbuf, no htp.
__global__ __launch_bounds__(512, 6) void k_fused(
    const float* __restrict__ rseq, const float* __restrict__ x,
    const unsigned short* __restrict__ buw,  // bwp; uwp contiguous after it
    const float* __restrict__ ub, const unsigned short* __restrict__ fftps,
    const float* __restrict__ fftpb, const float* __restrict__ fmix,
    const float* __restrict__ cvec, const float* __restrict__ hm,
    float* __restrict__ hs) {
  __shared__ short sRX[24576];  // r 32x512 @0, x 32x256 @16384
  __shared__ float red[640];    // stats: mean/rstd @512 (pairs), sdev @576
  const int t = threadIdx.x, w = t >> 6, lane = t & 63, lr = lane & 31, lh = lane >> 5;
  const int m0 = blockIdx.x * 32;
  const int bidx = m0 >> 13;

  // ---- stage r panel (8 f4/thread) + x panel (4 f4/thread) ----
#pragma unroll
  for (int i = 0; i < 8; ++i) {
    int c = t + i * 512;                 // 128 float4 per row
    int row = c >> 7, k0 = (c & 127) * 4;
    float4 v = *reinterpret_cast<const float4*>(rseq + (size_t)(m0 + row) * 512 + k0);
    uint2 p;
    p.x = cvtpk(v.x, v.y);
    p.y = cvtpk(v.z, v.w);
    *reinterpret_cast<uint2*>(&sRX[(k0 >> 3) * 256 + row * 8 + (k0 & 7)]) = p;
  }
#pragma unroll
  for (int i = 0; i < 4; ++i) {
    int c = t + i * 512;
    int row = c >> 6, k0 = (c & 63) * 4;
    float4 v = *reinterpret_cast<const float4*>(x + (size_t)(m0 + row) * 256 + k0);
    uint2 p;
    p.x = cvtpk(v.x, v.y);
    p.y = cvtpk(v.z, v.w);
    *reinterpret_cast<uint2*>(&sRX[16384 + (k0 >> 3) * 256 + row * 8 + (k0 & 7)]) = p;
  }
  barrier_lgkm();

  // ---- GEMM1: h_pre = [r,x] @ [Bw,Uw]^T, 48 half-steps (K=16) ----
  f32x16 acc[2];
#pragma unroll
  for (int ni = 0; ni < 2; ++ni)
#pragma unroll
    for (int e = 0; e < 16; ++e) acc[ni][e] = 0.f;
  short8 b0[2], b1[2];
  auto loadB1 = [&](int h, short8 (&bd)[2]) {
#pragma unroll
    for (int ni = 0; ni < 2; ++ni)
      bd[ni] = *reinterpret_cast<const short8*>(
          buw + (size_t)(h >> 1) * 16384 + ((h & 1) * 2 + lh) * 4096 +
          (64 * w + 32 * ni + lr) * 8);
  };
  auto mf1 = [&](int h, short8 (&bc)[2]) {
    short8 af = *reinterpret_cast<const short8*>(
        &sRX[(h * 2 + lh) * 256 + lr * 8]);
    __builtin_amdgcn_s_setprio(1);
#pragma unroll
    for (int ni = 0; ni < 2; ++ni)
      acc[ni] = mfma16(af, bc[ni], acc[ni]);
    __builtin_amdgcn_s_setprio(0);
  };
  loadB1(0, b0);
#pragma unroll
  for (int h = 0; h < 48; h += 2) {
    loadB1(h + 1, b1);
    mf1(h, b0);
    if (h + 2 < 48) loadB1(h + 2, b0);
    mf1(h + 1, b1);
  }

  // ---- epi1: gelu, LN stats (incl. sdev), write h_norm into r region ----
#pragma unroll
  for (int ni = 0; ni < 2; ++ni) {
    int col = 64 * w + 32 * ni + lr;
    float ubc = ub[col];
#pragma unroll
    for (int r = 0; r < 16; ++r) {
      float pre = acc[ni][r] + ubc;
      acc[ni][r] = 0.5f * pre * (1.f + erff(pre * 0.70710678118654752f));
    }
  }
#pragma unroll
  for (int r = 0; r < 16; ++r) {
    float s1 = acc[0][r] + acc[1][r];
    float s2 = acc[0][r] * acc[0][r] + acc[1][r] * acc[1][r];
#pragma unroll
    for (int m = 1; m <= 16; m <<= 1) { s1 += __shfl_xor(s1, m); s2 += __shfl_xor(s2, m); }
    int rl = (r & 3) + 8 * (r >> 2) + 4 * lh;
    if (lr == r) { red[w * 32 + rl] = s1; red[256 + w * 32 + rl] = s2; }
  }
  __syncthreads();                         // all GEMM1 panel reads done
  if (t < 32) {
    float s1 = 0.f, s2 = 0.f;
#pragma unroll
    for (int n = 0; n < 8; ++n) { s1 += red[n * 32 + t]; s2 += red[256 + n * 32 + t]; }
    float mean = s1 * (1.f / 512.f);
    float var = s2 * (1.f / 512.f) - mean * mean;
    float rstd = rsqrtf(var + 1e-5f);
    red[512 + t * 2] = mean;
    red[512 + t * 2 + 1] = rstd;
    red[576 + t] = sqrtf(var + 1e-5f);     // sdev for epi2 reconstruction
  }
  __syncthreads();
  auto loadB2 = [&](int h, short8 (&bd)[2]) {
#pragma unroll
    for (int ni = 0; ni < 2; ++ni)
      bd[ni] = *reinterpret_cast<const short8*>(
          fftps + (size_t)(h >> 1) * 16384 + ((h & 1) * 2 + lh) * 4096 +
          (64 * w + 32 * ni + lr) * 8);
  };
  loadB2(0, b0);                           // prefetch under h_norm writes
#pragma unroll
  for (int q = 0; q < 4; ++q) {
    float4 stA = *reinterpret_cast<float4*>(&red[512 + (8 * q + 4 * lh) * 2]);
    float4 stB = *reinterpret_cast<float4*>(&red[512 + (8 * q + 4 * lh) * 2 + 4]);
    float mean[4] = {stA.x, stA.z, stB.x, stB.z};
    float rstd[4] = {stA.y, stA.w, stB.y, stB.w};
#pragma unroll
    for (int ni = 0; ni < 2; ++ni) {
      int col = 64 * w + 32 * ni + lr;
#pragma unroll
      for (int e = 0; e < 4; ++e) {
        int r = 4 * q + e;
        float z = (acc[ni][r] - mean[e]) * rstd[e];
        int rloc = 8 * q + 4 * lh + e;
        sRX[(col >> 3) * 256 + rloc * 8 + (col & 7)] = (short)f2bf(z);
      }
    }
  }
#pragma unroll
  for (int ni = 0; ni < 2; ++ni)
#pragma unroll
    for (int e = 0; e < 16; ++e) acc[ni][e] = 0.f;
  barrier_lgkm();

  // ---- GEMM2: h_norm @ (fftp*g)^T, 32 half-steps ----
  auto mf2 = [&](int h, short8 (&bc)[2]) {
    short8 af = *reinterpret_cast<const short8*>(
        &sRX[(h * 2 + lh) * 256 + lr * 8]);
    __builtin_amdgcn_s_setprio(1);
#pragma unroll
    for (int ni = 0; ni < 2; ++ni)
      acc[ni] = mfma16(af, bc[ni], acc[ni]);
    __builtin_amdgcn_s_setprio(0);
  };
#pragma unroll
  for (int h = 0; h < 32; h += 2) {
    loadB2(h + 1, b1);
    mf2(h, b0);
    if (h + 2 < 32) loadB2(h + 2, b0);
    mf2(h + 1, b1);
  }

  // ---- epi2: combine (h~ reconstructed from LDS z + stats) ----
  const float sg = 1.f / (1.f + expf(-fmix[0]));
  const float s2f = sg * sg, oms = 1.f - sg;
#pragma unroll
  for (int ni = 0; ni < 2; ++ni) {
    int col = 64 * w + 32 * ni + lr;
    float base = s2f * cvec[col] + sg * fftpb[col] + 0.5f * hm[bidx * 512 + col];
    const int cb = (col >> 3) * 256 + (col & 7);
#pragma unroll
    for (int q = 0; q < 4; ++q)
#pragma unroll
      for (int e = 0; e < 4; ++e) {
        int r = 4 * q + e;
        int rloc = 8 * q + 4 * lh + e;
        float z = bf2f((unsigned short)sRX[cb + rloc * 8]);
        float ht = z * red[576 + rloc] + red[512 + rloc * 2];
        hs[(size_t)(m0 + rloc) * 512 + col] = oms * ht + s2f * acc[ni][r] + base;
      }
  }
}

extern "C" void kernel_launch(void* const* d_in, const int* in_sizes, int n_in,
                              void* d_out, int out_size, void* d_ws, size_t ws_size,
                              hipStream_t stream) {
  (void)in_sizes; (void)n_in; (void)out_size; (void)ws_size;
  const float* x     = (const float*)d_in[0];
  const float* Wxw   = (const float*)d_in[1];
  const float* Wxb   = (const float*)d_in[2];
  const float* resa  = (const float*)d_in[4];
  const float* Bw    = (const float*)d_in[6];
  const float* Uw    = (const float*)d_in[7];
  const float* Ub    = (const float*)d_in[8];
  const float* fg    = (const float*)d_in[9];
  const float* fb    = (const float*)d_in[10];
  const float* fftpw = (const float*)d_in[11];
  const float* fftpb = (const float*)d_in[12];
  const float* fmix  = (const float*)d_in[13];
  const float* mixl  = (const float*)d_in[14];
  const float* keyw  = (const float*)d_in[15];
  const float* keyb  = (const float*)d_in[16];
  const float* rmw   = (const float*)d_in[19];
  const float* rmb   = (const float*)d_in[20];
  const float* rng   = (const float*)d_in[21];
  const float* rnb   = (const float*)d_in[22];
  const float* mkeys = (const float*)d_in[23];
  const float* mvals = (const float*)d_in[24];
  const float* hebH  = (const float*)d_in[25];

  float* outp = (float*)d_out;
  float* hs   = outp;                               // (B,T,512)
  float* rout = outp + (size_t)65536 * 512;         // (B,T,512)

  unsigned short* wsu = (unsigned short*)d_ws;
  unsigned short* wxp    = wsu;                     // 131072
  unsigned short* keyp   = wsu + 131072;            // 98304
  unsigned short* bwp    = wsu + 229376;            // 262144 (uwp contiguous)
  unsigned short* uwp    = wsu + 491520;            // 131072
  unsigned short* fftps  = wsu + 622592;            // 262144
  float* wsf     = (float*)d_ws;
  float* partial = wsf + 524288;                    // 2048*128 = 262144
  float* q_ws    = wsf + 786432;                    // 1024
  float* hm      = wsf + 787456;                    // 4096
  float* cvec    = wsf + 791552;                    // 512

  k_wconv<<<3456, 256, 0, stream>>>(Wxw, keyw, Bw, Uw, fftpw, fg,
                                    wxp, keyp, bwp, uwp, fftps);
  k_cvec <<<2,    256, 0, stream>>>(fb, fftpw, cvec);
  k_rk   <<<2048, 512, 0, stream>>>(x, wxp, keyp, Wxb, resa, rng, rnb, keyb,
                                    rout, partial);
  k_qred <<<4,    256, 0, stream>>>(partial, q_ws);
  k_mem  <<<8,    256, 0, stream>>>(q_ws, mkeys, mvals, hebH, rmw, rmb, mixl, hm);
  k_fused<<<2048, 512, 0, stream>>>(rout, x, bwp, Ub, fftps, fftpb,
                                    fmix, cvec, hm, hs);
}

// Round 15
// 306.472 us; speedup vs baseline: 1.3100x; 1.3100x over previous
//
#include <hip/hip_runtime.h>
#include <cmath>

// CRSDCell bf16-MFMA pipeline, FINAL (round-13 best config, 306.6us):
//  - k_rk: fused r_seq + k/q partials (BM=32, panel-staged, split-K k-GEMM).
//  - k_fused: h~=gelu([r,x]@[Bw,Uw]^T+Ub) -> LN -> @(fftp*g)^T -> combine.
//    BM=32, launch_bounds(512,4) (2 blocks/CU, no spill), panels staged once
//    in k-slot LDS layout (conflict-free ds_read_b128), barrier-free GEMM
//    K-loops with depth-1 register B-prefetch (deeper variants spill).
//  - Weights pre-packed chunk-major P[k0][slot4][n][8]; bwp/uwp contiguous.
//  - v_cvt_pk_bf16_f32 for fp32->2xbf16 packing.
// FFT folds exactly: irfft(rfft(h)*s) = s*h. h_prev=r_prev=0 kills Wh/A terms.
// Design-space map (measured): BM=64 -20%; named depth-2/3 buffers spill;
// (512,6) spills; barrier variants null. This config is the corner optimum.

typedef __attribute__((ext_vector_type(8)))  short short8;
typedef __attribute__((ext_vector_type(16))) float f32x16;

__device__ __forceinline__ unsigned short f2bf(float f) {
  union { float f; unsigned u; } v; v.f = f;
  unsigned r = v.u + 0x7FFF + ((v.u >> 16) & 1);   // RTNE
  return (unsigned short)(r >> 16);
}
__device__ __forceinline__ unsigned cvtpk(float lo, float hi) {
  unsigned r;
  asm("v_cvt_pk_bf16_f32 %0, %1, %2" : "=v"(r) : "v"(lo), "v"(hi));
  return r;
}
__device__ __forceinline__ float bf2f(unsigned short h) {
  union { unsigned u; float f; } v; v.u = ((unsigned)h) << 16; return v.f;
}
__device__ __forceinline__ f32x16 mfma16(short8 a, short8 b, f32x16 c) {
  return __builtin_amdgcn_mfma_f32_32x32x16_bf16(a, b, c, 0, 0, 0);
}
__device__ __forceinline__ void barrier_lgkm() {
  asm volatile("s_waitcnt lgkmcnt(0)" ::: "memory");
  __builtin_amdgcn_s_barrier();
  __builtin_amdgcn_sched_barrier(0);
}

// ---------------- weight convert + pack ----------------
// packed offset for (n,k) in [N][K]: (k>>5)*N*32 + ((k>>3)&3)*N*8 + n*8 + (k&7)
__global__ __launch_bounds__(256) void k_wconv(
    const float* __restrict__ wx, const float* __restrict__ key,
    const float* __restrict__ bw, const float* __restrict__ uw,
    const float* __restrict__ fftpw, const float* __restrict__ fg,
    unsigned short* __restrict__ wxp, unsigned short* __restrict__ keyp,
    unsigned short* __restrict__ bwp, unsigned short* __restrict__ uwp,
    unsigned short* __restrict__ fftps) {
  int i = blockIdx.x * 256 + threadIdx.x;
  if (i >= 884736) return;
  float v; int n, k, N; unsigned short* dst;
  if (i < 131072)      { int j = i;          N = 512; k = j & 255; n = j >> 8; v = wx[j];  dst = wxp; }
  else if (i < 229376) { int j = i - 131072; N = 128; k = j % 768; n = j / 768; v = key[j]; dst = keyp; }
  else if (i < 491520) { int j = i - 229376; N = 512; k = j & 511; n = j >> 9; v = bw[j];  dst = bwp; }
  else if (i < 622592) { int j = i - 491520; N = 512; k = j & 255; n = j >> 8; v = uw[j];  dst = uwp; }
  else                 { int j = i - 622592; N = 512; k = j & 511; n = j >> 9; v = fftpw[j] * fg[k]; dst = fftps; }
  dst[(k >> 5) * (N * 32) + ((k >> 3) & 3) * (N * 8) + n * 8 + (k & 7)] = f2bf(v);
}

// ---------------- K_RK: r_seq + k/q partials (BM=32) ----------------
// LDS: sRX = [r slots 0..63 | x slots 64..95] (48KB), red 2.5KB
__global__ __launch_bounds__(512, 4) void k_rk(
    const float* __restrict__ x, const unsigned short* __restrict__ wxp,
    const unsigned short* __restrict__ keyp,
    const float* __restrict__ wxb, const float* __restrict__ resa,
    const float* __restrict__ rng, const float* __restrict__ rnb,
    const float* __restrict__ keyb,
    float* __restrict__ rout, float* __restrict__ partial) {
  __shared__ short sRX[24576];  // r 32x512 @0, x 32x256 @16384; kp overlays
  __shared__ float red[640];
  const int t = threadIdx.x, w = t >> 6, lane = t & 63, lr = lane & 31, lh = lane >> 5;
  const int m0 = blockIdx.x * 32;

  // ---- stage x panel (slots 64..95) ----
#pragma unroll
  for (int i = 0; i < 4; ++i) {
    int c = t + i * 512;                 // float4 idx; 64 per row
    int row = c >> 6, k0 = (c & 63) * 4;
    float4 v = *reinterpret_cast<const float4*>(x + (size_t)(m0 + row) * 256 + k0);
    uint2 p;
    p.x = cvtpk(v.x, v.y);
    p.y = cvtpk(v.z, v.w);
    *reinterpret_cast<uint2*>(&sRX[16384 + (k0 >> 3) * 256 + row * 8 + (k0 & 7)]) = p;
  }
  barrier_lgkm();

  // ---- GEMM0: r_pre = x @ Wx^T, 8 barrier-free steps ----
  f32x16 acc[2];
#pragma unroll
  for (int ni = 0; ni < 2; ++ni)
#pragma unroll
    for (int e = 0; e < 16; ++e) acc[ni][e] = 0.f;
  short8 b0[4], b1[4];
  auto loadB0 = [&](int s, short8 (&bd)[4]) {
#pragma unroll
    for (int kh = 0; kh < 2; ++kh)
#pragma unroll
      for (int ni = 0; ni < 2; ++ni)
        bd[kh * 2 + ni] = *reinterpret_cast<const short8*>(
            wxp + (size_t)s * 16384 + (kh * 2 + lh) * 4096 + (64 * w + 32 * ni + lr) * 8);
  };
  auto mf0 = [&](int s, short8 (&bc)[4]) {
    short8 af[2];
#pragma unroll
    for (int kh = 0; kh < 2; ++kh)
      af[kh] = *reinterpret_cast<const short8*>(
          &sRX[16384 + (s * 4 + kh * 2 + lh) * 256 + lr * 8]);
    __builtin_amdgcn_s_setprio(1);
#pragma unroll
    for (int kh = 0; kh < 2; ++kh)
#pragma unroll
      for (int ni = 0; ni < 2; ++ni)
        acc[ni] = mfma16(af[kh], bc[kh * 2 + ni], acc[ni]);
    __builtin_amdgcn_s_setprio(0);
  };
  loadB0(0, b0);
#pragma unroll
  for (int s = 0; s < 8; s += 2) {
    loadB0(s + 1, b1);
    mf0(s, b0);
    if (s + 2 < 8) loadB0(s + 2, b0);
    mf0(s + 1, b1);
  }

  // ---- epi0: z=(1-a)tanh(.+b), LN, write rout + r panel ----
#pragma unroll
  for (int ni = 0; ni < 2; ++ni) {
    int col = 64 * w + 32 * ni + lr;
    float al = 1.f / (1.f + expf(-resa[col >> 7]));
    float oma = 1.f - al, bbv = wxb[col];
#pragma unroll
    for (int r = 0; r < 16; ++r)
      acc[ni][r] = oma * tanhf(acc[ni][r] + bbv);
  }
#pragma unroll
  for (int r = 0; r < 16; ++r) {
    float s1 = acc[0][r] + acc[1][r];
    float s2 = acc[0][r] * acc[0][r] + acc[1][r] * acc[1][r];
#pragma unroll
    for (int m = 1; m <= 16; m <<= 1) { s1 += __shfl_xor(s1, m); s2 += __shfl_xor(s2, m); }
    int rl = (r & 3) + 8 * (r >> 2) + 4 * lh;
    if (lr == r) { red[w * 32 + rl] = s1; red[256 + w * 32 + rl] = s2; }
  }
  __syncthreads();
  if (t < 32) {
    float s1 = 0.f, s2 = 0.f;
#pragma unroll
    for (int n = 0; n < 8; ++n) { s1 += red[n * 32 + t]; s2 += red[256 + n * 32 + t]; }
    float mean = s1 * (1.f / 512.f);
    float var = s2 * (1.f / 512.f) - mean * mean;
    float rstd = rsqrtf(var + 1e-5f);
    red[512 + t * 2] = mean;
    red[512 + t * 2 + 1] = rstd;
  }
  __syncthreads();
#pragma unroll
  for (int q = 0; q < 4; ++q) {
    float4 stA = *reinterpret_cast<float4*>(&red[512 + (8 * q + 4 * lh) * 2]);
    float4 stB = *reinterpret_cast<float4*>(&red[512 + (8 * q + 4 * lh) * 2 + 4]);
    float mean[4] = {stA.x, stA.z, stB.x, stB.z};
    float rstd[4] = {stA.y, stA.w, stB.y, stB.w};
#pragma unroll
    for (int ni = 0; ni < 2; ++ni) {
      int col = 64 * w + 32 * ni + lr;
      float g = rng[col], bbv = rnb[col];
#pragma unroll
      for (int e = 0; e < 4; ++e) {
        int r = 4 * q + e;
        int rloc = 8 * q + 4 * lh + e;
        float val = (acc[ni][r] - mean[e]) * rstd[e] * g + bbv;
        rout[(size_t)(m0 + rloc) * 512 + col] = val;
        sRX[(col >> 3) * 256 + rloc * 8 + (col & 7)] = (short)f2bf(val);
      }
    }
  }
  barrier_lgkm();

  // ---- GEMM_k: k = [r,x] @ key^T, split-K over 2 wave-groups ----
  const int g = w >> 2, nw2 = w & 3;     // group, wave-in-group (32 cols each)
  f32x16 ak;
#pragma unroll
  for (int e = 0; e < 16; ++e) ak[e] = 0.f;
  short8 kb0[2], kb1[2];
  auto loadBk = [&](int gc, short8 (&bd)[2]) {
#pragma unroll
    for (int kh = 0; kh < 2; ++kh)
      bd[kh] = *reinterpret_cast<const short8*>(
          keyp + (size_t)gc * 4096 + (kh * 2 + lh) * 1024 + (32 * nw2 + lr) * 8);
  };
  auto mfk = [&](int gc, short8 (&bc)[2]) {
    short8 af[2];
#pragma unroll
    for (int kh = 0; kh < 2; ++kh)
      af[kh] = *reinterpret_cast<const short8*>(
          &sRX[(gc * 4 + kh * 2 + lh) * 256 + lr * 8]);
    __builtin_amdgcn_s_setprio(1);
#pragma unroll
    for (int kh = 0; kh < 2; ++kh)
      ak = mfma16(af[kh], bc[kh], ak);
    __builtin_amdgcn_s_setprio(0);
  };
  const int gbase = g * 12;
  loadBk(gbase, kb0);
#pragma unroll
  for (int s = 0; s < 12; s += 2) {
    loadBk(gbase + s + 1, kb1);
    mfk(gbase + s, kb0);
    if (s + 2 < 12) loadBk(gbase + s + 2, kb0);
    mfk(gbase + s + 1, kb1);
  }
  __syncthreads();                        // all panel reads done
  float* kp = reinterpret_cast<float*>(sRX);  // kp[g][32 rows][128 cols]
#pragma unroll
  for (int r = 0; r < 16; ++r) {
    int rr = (r & 3) + 8 * (r >> 2) + 4 * lh;
    kp[g * 4096 + rr * 128 + nw2 * 32 + lr] = ak[r];
  }
  __syncthreads();
  // pass1: per-row sumsq -> scale
  {
    int rr = t >> 4, cg = t & 15;
    float s1 = 0.f;
#pragma unroll
    for (int j = 0; j < 8; ++j) {
      int c = cg * 8 + j;
      float v = kp[rr * 128 + c] + kp[4096 + rr * 128 + c] + keyb[c];
      s1 += v * v;
    }
#pragma unroll
    for (int m = 1; m <= 8; m <<= 1) s1 += __shfl_xor(s1, m);
    if (cg == 0) red[rr] = 1.f / fmaxf(sqrtf(s1), 1e-8f);
  }
  __syncthreads();
  // pass2: column partials of l2norm(k)
  if (t < 128) {
    float p = 0.f;
    float bb = keyb[t];
#pragma unroll 4
    for (int rr = 0; rr < 32; ++rr)
      p += (kp[rr * 128 + t] + kp[4096 + rr * 128 + t] + bb) * red[rr];
    partial[(size_t)blockIdx.x * 128 + t] = p;
  }
}

// ---------------- q reduce (2048 partial blocks, 256 per batch) -------------
__global__ __launch_bounds__(256) void k_qred(const float* __restrict__ partial,
                                              float* __restrict__ q_ws) {
  int gid = blockIdx.x * 256 + threadIdx.x;   // 0..1023
  int b = gid >> 7, c = gid & 127;
  float s = 0.f;
  for (int i = 0; i < 256; ++i) s += partial[(size_t)(b * 256 + i) * 128 + c];
  q_ws[gid] = s * (1.f / 8192.f);
}

// ---------------- cvec = fftn_b @ fftp_w^T (raw fftp) ----------------
__global__ __launch_bounds__(256) void k_cvec(const float* __restrict__ fb,
                                              const float* __restrict__ fftpw,
                                              float* __restrict__ cvec) {
  int o = blockIdx.x * 256 + threadIdx.x;     // 0..511
  const float* w = fftpw + (size_t)o * 512;
  float s = 0.f;
  for (int k = 0; k < 512; ++k) s += fb[k] * w[k];
  cvec[o] = s;
}

// ---------------- memory (episodic + hebbian) ----------------
__global__ __launch_bounds__(256) void k_mem(
    const float* __restrict__ q_ws, const float* __restrict__ mkeys,
    const float* __restrict__ mvals, const float* __restrict__ hebH,
    const float* __restrict__ rmw, const float* __restrict__ rmb,
    const float* __restrict__ mixl, float* __restrict__ hm) {
  const int b = blockIdx.x, t = threadIdx.x;
  __shared__ float qv[128];
  __shared__ float ssim[256];
  __shared__ float red[256];
  __shared__ float tval[8];
  __shared__ int tidx[8];
  __shared__ float wsm[8];
  __shared__ float vcs[128];

  if (t < 128) qv[t] = q_ws[b * 128 + t];
  __syncthreads();
  red[t] = (t < 128) ? qv[t] * qv[t] : 0.f;
  __syncthreads();
  for (int s = 128; s > 0; s >>= 1) {
    if (t < s) red[t] += red[t + s];
    __syncthreads();
  }
  float qsc = 1.f / fmaxf(sqrtf(red[0]), 1e-8f);
  {
    const float* mk = mkeys + ((size_t)b * 256 + t) * 128;
    float dot = 0.f, ms = 0.f;
    for (int k = 0; k < 128; ++k) { float mv = mk[k]; dot += qv[k] * mv; ms += mv * mv; }
    ssim[t] = dot * qsc / fmaxf(sqrtf(ms), 1e-8f);
  }
  __syncthreads();
  for (int it = 0; it < 8; ++it) {
    if (t < 64) {
      float bv = -1e30f; int bi = 0;
#pragma unroll
      for (int u = 0; u < 4; ++u) {
        int m = t * 4 + u;
        float v = ssim[m];
        if (v > bv) { bv = v; bi = m; }
      }
      for (int off = 32; off; off >>= 1) {
        float ov = __shfl_xor(bv, off, 64);
        int oi = __shfl_xor(bi, off, 64);
        if (ov > bv || (ov == bv && oi < bi)) { bv = ov; bi = oi; }
      }
      if (t == 0) { tval[it] = bv; tidx[it] = bi; ssim[bi] = -1e30f; }
    }
    __syncthreads();
  }
  if (t == 0) {
    float m0 = tval[0], sum = 0.f, e[8];
#pragma unroll
    for (int i = 0; i < 8; ++i) { e[i] = expf(tval[i] - m0); sum += e[i]; }
#pragma unroll
    for (int i = 0; i < 8; ++i) wsm[i] = e[i] / sum;
  }
  __syncthreads();
  float mix = 1.f / (1.f + expf(-mixl[0]));
  if (t < 128) {
    float vh = 0.f;
#pragma unroll
    for (int i = 0; i < 8; ++i) vh += wsm[i] * mvals[((size_t)b * 256 + tidx[i]) * 128 + t];
    float vhb = 0.f;
    const float* H = hebH + (size_t)b * 128 * 128;
    for (int k = 0; k < 128; ++k) vhb += qv[k] * H[k * 128 + t];
    vcs[t] = mix * vh + (1.f - mix) * vhb;
  }
  __syncthreads();
  for (int h = t; h < 512; h += 256) {
    float sum = rmb[h];
    const float* wr = rmw + (size_t)h * 128;
    for (int v = 0; v < 128; ++v) sum += vcs[v] * wr[v];
    hm[b * 512 + h] = sum;
  }
}

// ---------------- fused h_tilde -> LN -> fftp GEMM -> hs (BM=32) ------------
// LDS: sRX = [r 0..63 | x 64..95] 48KB (h_norm overlays r) + red 2.5K
__global__ __launch_bounds__(512, 4) void k_fused(
    const float* __restrict__ rseq, const float* __restrict__ x,
    const unsigned short* __restrict__ buw,  // bwp; uwp contiguous after it
    const float* __restrict__ ub, const unsigned short* __restrict__ fftps,
    const float* __restrict__ fftpb, const float* __restrict__ fmix,
    const float* __restrict__ cvec, const float* __restrict__ hm,
    float* __restrict__ hs) {
  __shared__ short sRX[24576];  // r 32x512 @0, x 32x256 @16384
  __shared__ float red[640];
  const int t = threadIdx.x, w = t >> 6, lane = t & 63, lr = lane & 31, lh = lane >> 5;
  const int m0 = blockIdx.x * 32;
  const int bidx = m0 >> 13;

  // ---- stage r panel (8 f4/thread) + x panel (4 f4/thread) ----
#pragma unroll
  for (int i = 0; i < 8; ++i) {
    int c = t + i * 512;                 // 128 float4 per row
    int row = c >> 7, k0 = (c & 127) * 4;
    float4 v = *reinterpret_cast<const float4*>(rseq + (size_t)(m0 + row) * 512 + k0);
    uint2 p;
    p.x = cvtpk(v.x, v.y);
    p.y = cvtpk(v.z, v.w);
    *reinterpret_cast<uint2*>(&sRX[(k0 >> 3) * 256 + row * 8 + (k0 & 7)]) = p;
  }
#pragma unroll
  for (int i = 0; i < 4; ++i) {
    int c = t + i * 512;
    int row = c >> 6, k0 = (c & 63) * 4;
    float4 v = *reinterpret_cast<const float4*>(x + (size_t)(m0 + row) * 256 + k0);
    uint2 p;
    p.x = cvtpk(v.x, v.y);
    p.y = cvtpk(v.z, v.w);
    *reinterpret_cast<uint2*>(&sRX[16384 + (k0 >> 3) * 256 + row * 8 + (k0 & 7)]) = p;
  }
  barrier_lgkm();

  // ---- GEMM1: h_pre = [r,x] @ [Bw,Uw]^T, 24 barrier-free steps ----
  f32x16 acc[2];
#pragma unroll
  for (int ni = 0; ni < 2; ++ni)
#pragma unroll
    for (int e = 0; e < 16; ++e) acc[ni][e] = 0.f;
  short8 b0[4], b1[4];
  auto loadB1 = [&](int s, short8 (&bd)[4]) {
#pragma unroll
    for (int kh = 0; kh < 2; ++kh)
#pragma unroll
      for (int ni = 0; ni < 2; ++ni)
        bd[kh * 2 + ni] = *reinterpret_cast<const short8*>(
            buw + (size_t)s * 16384 + (kh * 2 + lh) * 4096 + (64 * w + 32 * ni + lr) * 8);
  };
  auto mf1 = [&](int s, short8 (&bc)[4]) {
    short8 af[2];
#pragma unroll
    for (int kh = 0; kh < 2; ++kh)
      af[kh] = *reinterpret_cast<const short8*>(
          &sRX[(s * 4 + kh * 2 + lh) * 256 + lr * 8]);
    __builtin_amdgcn_s_setprio(1);
#pragma unroll
    for (int kh = 0; kh < 2; ++kh)
#pragma unroll
      for (int ni = 0; ni < 2; ++ni)
        acc[ni] = mfma16(af[kh], bc[kh * 2 + ni], acc[ni]);
    __builtin_amdgcn_s_setprio(0);
  };
  loadB1(0, b0);
#pragma unroll
  for (int s = 0; s < 24; s += 2) {
    loadB1(s + 1, b1);
    mf1(s, b0);
    if (s + 2 < 24) loadB1(s + 2, b0);
    mf1(s + 1, b1);
  }

  // ---- epi1: gelu, LN stats, pack h~, write h_norm into r region ----
#pragma unroll
  for (int ni = 0; ni < 2; ++ni) {
    int col = 64 * w + 32 * ni + lr;
    float ubc = ub[col];
#pragma unroll
    for (int r = 0; r < 16; ++r) {
      float pre = acc[ni][r] + ubc;
      acc[ni][r] = 0.5f * pre * (1.f + erff(pre * 0.70710678118654752f));
    }
  }
#pragma unroll
  for (int r = 0; r < 16; ++r) {
    float s1 = acc[0][r] + acc[1][r];
    float s2 = acc[0][r] * acc[0][r] + acc[1][r] * acc[1][r];
#pragma unroll
    for (int m = 1; m <= 16; m <<= 1) { s1 += __shfl_xor(s1, m); s2 += __shfl_xor(s2, m); }
    int rl = (r & 3) + 8 * (r >> 2) + 4 * lh;
    if (lr == r) { red[w * 32 + rl] = s1; red[256 + w * 32 + rl] = s2; }
  }
  __syncthreads();                         // all GEMM1 panel reads done
  if (t < 32) {
    float s1 = 0.f, s2 = 0.f;
#pragma unroll
    for (int n = 0; n < 8; ++n) { s1 += red[n * 32 + t]; s2 += red[256 + n * 32 + t]; }
    float mean = s1 * (1.f / 512.f);
    float var = s2 * (1.f / 512.f) - mean * mean;
    float rstd = rsqrtf(var + 1e-5f);
    red[512 + t * 2] = mean;
    red[512 + t * 2 + 1] = rstd;
  }
  __syncthreads();
  unsigned htp[2][8];
#pragma unroll
  for (int ni = 0; ni < 2; ++ni)
#pragma unroll
    for (int p = 0; p < 8; ++p)
      htp[ni][p] = cvtpk(acc[ni][2 * p], acc[ni][2 * p + 1]);
  auto loadB2 = [&](int s, short8 (&bd)[4]) {
#pragma unroll
    for (int kh = 0; kh < 2; ++kh)
#pragma unroll
      for (int ni = 0; ni < 2; ++ni)
        bd[kh * 2 + ni] = *reinterpret_cast<const short8*>(
            fftps + (size_t)s * 16384 + (kh * 2 + lh) * 4096 + (64 * w + 32 * ni + lr) * 8);
  };
  loadB2(0, b0);                           // prefetch under h_norm writes
#pragma unroll
  for (int q = 0; q < 4; ++q) {
    float4 stA = *reinterpret_cast<float4*>(&red[512 + (8 * q + 4 * lh) * 2]);
    float4 stB = *reinterpret_cast<float4*>(&red[512 + (8 * q + 4 * lh) * 2 + 4]);
    float mean[4] = {stA.x, stA.z, stB.x, stB.z};
    float rstd[4] = {stA.y, stA.w, stB.y, stB.w};
#pragma unroll
    for (int ni = 0; ni < 2; ++ni) {
      int col = 64 * w + 32 * ni + lr;
#pragma unroll
      for (int e = 0; e < 4; ++e) {
        int r = 4 * q + e;
        float z = (acc[ni][r] - mean[e]) * rstd[e];
        int rloc = 8 * q + 4 * lh + e;
        sRX[(col >> 3) * 256 + rloc * 8 + (col & 7)] = (short)f2bf(z);
      }
    }
  }
#pragma unroll
  for (int ni = 0; ni < 2; ++ni)
#pragma unroll
    for (int e = 0; e < 16; ++e) acc[ni][e] = 0.f;
  barrier_lgkm();

  // ---- GEMM2: h_norm @ (fftp*g)^T, 16 barrier-free steps ----
  auto mf2 = [&](int s, short8 (&bc)[4]) {
    short8 af[2];
#pragma unroll
    for (int kh = 0; kh < 2; ++kh)
      af[kh] = *reinterpret_cast<const short8*>(
          &sRX[(s * 4 + kh * 2 + lh) * 256 + lr * 8]);
    __builtin_amdgcn_s_setprio(1);
#pragma unroll
    for (int kh = 0; kh < 2; ++kh)
#pragma unroll
      for (int ni = 0; ni < 2; ++ni)
        acc[ni] = mfma16(af[kh], bc[kh * 2 + ni], acc[ni]);
    __builtin_amdgcn_s_setprio(0);
  };
#pragma unroll
  for (int s = 0; s < 16; s += 2) {
    loadB2(s + 1, b1);
    mf2(s, b0);
    if (s + 2 < 16) loadB2(s + 2, b0);
    mf2(s + 1, b1);
  }

  // ---- epi2: combine ----
  const float sg = 1.f / (1.f + expf(-fmix[0]));
  const float s2f = sg * sg, oms = 1.f - sg;
#pragma unroll
  for (int ni = 0; ni < 2; ++ni) {
    int col = 64 * w + 32 * ni + lr;
    float base = s2f * cvec[col] + sg * fftpb[col] + 0.5f * hm[bidx * 512 + col];
#pragma unroll
    for (int p = 0; p < 8; ++p) {
      unsigned pk = htp[ni][p];
      int r0 = 2 * p;
      int rloc = (r0 & 3) + 8 * (r0 >> 2) + 4 * lh;
      float o0 = oms * bf2f((unsigned short)(pk & 0xFFFF)) + s2f * acc[ni][r0] + base;
      float o1 = oms * bf2f((unsigned short)(pk >> 16)) + s2f * acc[ni][r0 + 1] + base;
      hs[(size_t)(m0 + rloc) * 512 + col] = o0;
      hs[(size_t)(m0 + rloc + 1) * 512 + col] = o1;
    }
  }
}

extern "C" void kernel_launch(void* const* d_in, const int* in_sizes, int n_in,
                              void* d_out, int out_size, void* d_ws, size_t ws_size,
                              hipStream_t stream) {
  (void)in_sizes; (void)n_in; (void)out_size; (void)ws_size;
  const float* x     = (const float*)d_in[0];
  const float* Wxw   = (const float*)d_in[1];
  const float* Wxb   = (const float*)d_in[2];
  const float* resa  = (const float*)d_in[4];
  const float* Bw    = (const float*)d_in[6];
  const float* Uw    = (const float*)d_in[7];
  const float* Ub    = (const float*)d_in[8];
  const float* fg    = (const float*)d_in[9];
  const float* fb    = (const float*)d_in[10];
  const float* fftpw = (const float*)d_in[11];
  const float* fftpb = (const float*)d_in[12];
  const float* fmix  = (const float*)d_in[13];
  const float* mixl  = (const float*)d_in[14];
  const float* keyw  = (const float*)d_in[15];
  const float* keyb  = (const float*)d_in[16];
  const float* rmw   = (const float*)d_in[19];
  const float* rmb   = (const float*)d_in[20];
  const float* rng   = (const float*)d_in[21];
  const float* rnb   = (const float*)d_in[22];
  const float* mkeys = (const float*)d_in[23];
  const float* mvals = (const float*)d_in[24];
  const float* hebH  = (const float*)d_in[25];

  float* outp = (float*)d_out;
  float* hs   = outp;                               // (B,T,512)
  float* rout = outp + (size_t)65536 * 512;         // (B,T,512)

  unsigned short* wsu = (unsigned short*)d_ws;
  unsigned short* wxp    = wsu;                     // 131072
  unsigned short* keyp   = wsu + 131072;            // 98304
  unsigned short* bwp    = wsu + 229376;            // 262144 (uwp contiguous)
  unsigned short* uwp    = wsu + 491520;            // 131072
  unsigned short* fftps  = wsu + 622592;            // 262144
  float* wsf     = (float*)d_ws;
  float* partial = wsf + 524288;                    // 2048*128 = 262144
  float* q_ws    = wsf + 786432;                    // 1024
  float* hm      = wsf + 787456;                    // 4096
  float* cvec    = wsf + 791552;                    // 512

  k_wconv<<<3456, 256, 0, stream>>>(Wxw, keyw, Bw, Uw, fftpw, fg,
                                    wxp, keyp, bwp, uwp, fftps);
  k_cvec <<<2,    256, 0, stream>>>(fb, fftpw, cvec);
  k_rk   <<<2048, 512, 0, stream>>>(x, wxp, keyp, Wxb, resa, rng, rnb, keyb,
                                    rout, partial);
  k_qred <<<4,    256, 0, stream>>>(partial, q_ws);
  k_mem  <<<8,    256, 0, stream>>>(q_ws, mkeys, mvals, hebH, rmw, rmb, mixl, hm);
  k_fused<<<2048, 512, 0, stream>>>(rout, x, bwp, Ub, fftps, fftpb,
                                    fmix, cvec, hm, hs);
}